// Round 11
// baseline (503.662 us; speedup 1.0000x reference)
//
#include <hip/hip_runtime.h>
#include <hip/hip_fp16.h>

#define NN 50000
#define NGROUP 3125   // NN / 16 (exact)
#define NCHUNK 391    // ceil(NN / 128)
#define CHCAP 3072    // bucket capacity per chunk (expected ~2046)
#define SLAB 2048
#define BN_EPS 1e-5f

typedef unsigned int uint;
typedef unsigned short ushort;
typedef _Float16 half8 __attribute__((ext_vector_type(8)));
typedef float floatx4 __attribute__((ext_vector_type(4)));

__device__ __forceinline__ int aswz(int slot) { return slot ^ ((slot >> 4) & 7); }

__device__ __forceinline__ float h_lo(uint u) {
    return __half2float(__ushort_as_half((ushort)(u & 0xFFFFu)));
}
__device__ __forceinline__ float h_hi(uint u) {
    return __half2float(__ushort_as_half((ushort)(u >> 16)));
}
__device__ __forceinline__ void unpack8(uint4 v, float* f) {
    f[0] = h_lo(v.x); f[1] = h_hi(v.x);
    f[2] = h_lo(v.y); f[3] = h_hi(v.y);
    f[4] = h_lo(v.z); f[5] = h_hi(v.z);
    f[6] = h_lo(v.w); f[7] = h_hi(v.w);
}

// ================= CSR build: LDS-sorted buckets, chunk-local fills =================
// phase A: sort 2048-edge slabs by 128-row chunk in LDS, append runs to global buckets.
__global__ __launch_bounds__(256) void sortA_kernel(
    const int* __restrict__ ei, int* __restrict__ gcur,
    uint* __restrict__ bucket, int E)
{
    __shared__ int s_hist[NCHUNK];
    __shared__ int s_offs[NCHUNK];
    __shared__ int s_cur[NCHUNK];
    __shared__ int s_gb[NCHUNK];
    __shared__ int s_scanA[512], s_scanB[512];
    __shared__ uint s_sorted[SLAB];

    const int tid  = threadIdx.x;
    const int base = blockIdx.x * SLAB;
    const int cnt  = min(SLAB, E - base);

    for (int i = tid; i < NCHUNK; i += 256) s_hist[i] = 0;
    __syncthreads();

    uint pk[SLAB / 256];
    int nloc = 0;
    for (int i = tid; i < cnt; i += 256) {
        int src = ei[base + i];
        int dst = ei[E + base + i];
        int c = dst >> 7;
        pk[nloc++] = (uint)src | ((uint)(dst & 127) << 16) | ((uint)c << 23);
        atomicAdd(&s_hist[c], 1);
    }
    __syncthreads();
    for (int i = tid; i < 512; i += 256) s_scanA[i] = (i < NCHUNK) ? s_hist[i] : 0;
    __syncthreads();
    int* sa = s_scanA; int* sb = s_scanB;
    for (int off = 1; off < 512; off <<= 1) {
        for (int i = tid; i < 512; i += 256)
            sb[i] = sa[i] + ((i >= off) ? sa[i - off] : 0);
        __syncthreads();
        int* t = sa; sa = sb; sb = t;
    }
    for (int i = tid; i < NCHUNK; i += 256) {
        int excl = sa[i] - s_hist[i];
        s_offs[i] = excl;
        s_cur[i]  = excl;
    }
    __syncthreads();
    for (int k = 0; k < nloc; k++) {
        int c = pk[k] >> 23;
        int pos = atomicAdd(&s_cur[c], 1);
        s_sorted[pos] = pk[k];
    }
    __syncthreads();
    for (int c = tid; c < NCHUNK; c += 256) {
        int n = s_hist[c];
        s_gb[c] = n ? atomicAdd(&gcur[c], n) : 0;
    }
    __syncthreads();
    for (int i = tid; i < cnt; i += 256) {
        uint v = s_sorted[i];
        int c = v >> 23;
        int li = i - s_offs[c];
        bucket[(size_t)c * CHCAP + s_gb[c] + li] = v;
    }
}

// phase B: one block per chunk — inline base scan + per-row hist/scan -> rowPtr + dense fill.
__global__ __launch_bounds__(256) void fillB_kernel(
    const uint* __restrict__ bucket, const int* __restrict__ gcur,
    int* __restrict__ rowPtr, int* __restrict__ csr_src)
{
    __shared__ int s_hist[128];
    __shared__ int s_excl[128];
    __shared__ int s_cur[128];
    __shared__ int s_ws[4];
    __shared__ int s_base;
    const int c = blockIdx.x;
    const int tid = threadIdx.x;
    const int cnt = gcur[c];
    const int row0 = c * 128;

    // base = exclusive prefix sum of gcur[0..c)
    int part = 0;
    for (int i = tid; i < c; i += 256) part += gcur[i];
    #pragma unroll
    for (int off = 32; off >= 1; off >>= 1) part += __shfl_down(part, off, 64);
    if ((tid & 63) == 0) s_ws[tid >> 6] = part;
    if (tid < 128) s_hist[tid] = 0;
    __syncthreads();
    if (tid == 0) s_base = s_ws[0] + s_ws[1] + s_ws[2] + s_ws[3];
    __syncthreads();
    const int base = s_base;
    if (tid == 0 && c == NCHUNK - 1) rowPtr[NN] = base + cnt;

    for (int i = tid; i < cnt; i += 256) {
        uint v = bucket[(size_t)c * CHCAP + i];
        atomicAdd(&s_hist[(v >> 16) & 127], 1);
    }
    __syncthreads();
    if (tid < 128) {
        int lane = tid & 63;
        int v = s_hist[tid];
        int incl = v;
        #pragma unroll
        for (int off = 1; off < 64; off <<= 1) {
            int t = __shfl_up(incl, off, 64);
            if (lane >= off) incl += t;
        }
        s_excl[tid] = incl - v;
    }
    __syncthreads();
    if (tid < 128) {
        int excl = s_excl[tid];
        if (tid >= 64) excl += s_excl[63] + s_hist[63];
        s_cur[tid] = excl;
        int row = row0 + tid;
        if (row < NN) rowPtr[row] = base + excl;
    }
    __syncthreads();
    for (int i = tid; i < cnt; i += 256) {
        uint v = bucket[(size_t)c * CHCAP + i];
        int dl  = (v >> 16) & 127;
        int src = v & 0xFFFFu;
        int ofs = atomicAdd(&s_cur[dl], 1);
        csr_src[base + ofs] = src;
    }
}

// ======== proj: y = W_a^T * z, z = BNReLU(h_in) [APPLY] or cvt(x) [layer 1] ========
template<int FIN, bool APPLY>
__global__ __launch_bounds__(256, 4) void proj_kernel(
    const void* __restrict__ in_v,
    const float* __restrict__ stats_in, const float* __restrict__ g_in,
    const float* __restrict__ be_in,
    const float* __restrict__ wa,
    ushort* __restrict__ y_out)
{
    constexpr int KC = FIN / 32;
    __shared__ __align__(16) _Float16 s_B[FIN * 64];
    __shared__ __align__(16) _Float16 s_Y[4][1024];

    const int tid = threadIdx.x, w = tid >> 6, lane = tid & 63;
    const int q = lane >> 4, mm = lane & 15;

    for (int i = tid; i < FIN * 64; i += 256) {
        int j = i & 7, l = (i >> 3) & 63, t = i >> 9;
        int kc = t >> 2, nt = t & 3;
        int k = kc * 32 + (l >> 4) * 8 + j;
        int n = nt * 16 + (l & 15);
        s_B[i] = (_Float16)wa[k * 64 + n];
    }

    float scv[2][8], shv[2][8];
    if (APPLY) {
        #pragma unroll
        for (int kc = 0; kc < 2; kc++)
            #pragma unroll
            for (int j = 0; j < 8; j++) {
                int c = kc * 32 + q * 8 + j;
                float mean = stats_in[c] * (1.0f / NN);
                float var  = stats_in[64 + c] * (1.0f / NN) - mean * mean;
                float rstd = rsqrtf(var + BN_EPS);
                float s    = rstd * g_in[c];
                scv[kc][j] = s;
                shv[kc][j] = be_in[c] - mean * s;
            }
    }
    __syncthreads();

    int g = blockIdx.x * 4 + w;
    if (g >= NGROUP) return;
    const int row = g * 16 + mm;

    half8 af[KC];
    if (FIN == 128) {
        const float* xin = (const float*)in_v;
        #pragma unroll
        for (int kc = 0; kc < KC; kc++) {
            const float* p = xin + (size_t)row * 128 + kc * 32 + q * 8;
            float4 a = *(const float4*)p;
            float4 b = *(const float4*)(p + 4);
            half8 hv;
            hv[0] = (_Float16)a.x; hv[1] = (_Float16)a.y;
            hv[2] = (_Float16)a.z; hv[3] = (_Float16)a.w;
            hv[4] = (_Float16)b.x; hv[5] = (_Float16)b.y;
            hv[6] = (_Float16)b.z; hv[7] = (_Float16)b.w;
            af[kc] = hv;
        }
    } else {
        const ushort* hin = (const ushort*)in_v;
        #pragma unroll
        for (int kc = 0; kc < KC; kc++) {
            uint4 vv = *(const uint4*)(hin + (size_t)row * 64 + kc * 32 + q * 8);
            float f[8]; unpack8(vv, f);
            half8 hv;
            #pragma unroll
            for (int j = 0; j < 8; j++) {
                float z = APPLY ? fmaxf(fmaf(f[j], scv[kc][j], shv[kc][j]), 0.0f) : f[j];
                hv[j] = (_Float16)z;
            }
            af[kc] = hv;
        }
    }

    floatx4 acc[4] = {};
    #pragma unroll
    for (int nt = 0; nt < 4; nt++)
        #pragma unroll
        for (int kc = 0; kc < KC; kc++) {
            half8 bf = *(const half8*)(s_B + ((size_t)(kc * 4 + nt) * 64 + lane) * 8);
            acc[nt] = __builtin_amdgcn_mfma_f32_16x16x32_f16(af[kc], bf, acc[nt], 0, 0, 0);
        }

    _Float16* s_Yw = &s_Y[w][0];
    #pragma unroll
    for (int nt = 0; nt < 4; nt++)
        #pragma unroll
        for (int r = 0; r < 4; r++)
            s_Yw[(q * 4 + r) * 64 + nt * 16 + mm] = (_Float16)acc[nt][r];
    half8 t0 = *(const half8*)(s_Yw + lane * 8);
    half8 t1 = *(const half8*)(s_Yw + 512 + lane * 8);
    half8* dst = (half8*)((_Float16*)y_out + (size_t)g * 1024);
    dst[lane] = t0;
    dst[64 + lane] = t1;
}

// ======== gather: wave-PAIR per 16-row group. Each wave gathers 8 rows (4-row
// interleaved, value-prefetched), pair shares A tile in LDS, each wave does half
// the GEMM2 n-tiles + epilogue. 512 thr = 8 waves = 4 groups/block. ========
__global__ __launch_bounds__(512, 6) void gin_gather_kernel(
    const ushort* __restrict__ y,
    const int* __restrict__ rowPtr, const int* __restrict__ csr_src,
    const float* __restrict__ eps_p, const float* __restrict__ ba,
    const float* __restrict__ wb, const float* __restrict__ bb,
    ushort* __restrict__ h_out, float* __restrict__ stats_out)
{
    __shared__ __align__(16) _Float16 s_B2[64 * 64];
    __shared__ __align__(16) _Float16 s_A[4][1024];   // pair-shared A fragments
    __shared__ __align__(16) _Float16 s_T[4][1024];   // pair-shared D tile
    __shared__ float s_red[8][32];

    const int tid = threadIdx.x, w = tid >> 6, lane = tid & 63;
    const int p = w >> 1, sub = w & 1;
    const int cc = lane & 7, gph = lane >> 3;
    const int q = lane >> 4, mm = lane & 15;

    for (int i = tid; i < 64 * 64; i += 512) {
        int j = i & 7, l = (i >> 3) & 63, t = i >> 9;
        int kc = t >> 2, nt = t & 3;
        int k = kc * 32 + (l >> 4) * 8 + j;
        int n = nt * 16 + (l & 15);
        s_B2[i] = (_Float16)wb[k * 64 + n];
    }

    const float eps1 = 1.0f + eps_p[0];
    float bav[8];
    #pragma unroll
    for (int j = 0; j < 8; j++) bav[j] = ba[8 * cc + j];
    float bbv[2];
    #pragma unroll
    for (int ntl = 0; ntl < 2; ntl++) bbv[ntl] = bb[(sub * 2 + ntl) * 16 + mm];
    __syncthreads();

    const int g = blockIdx.x * 4 + p;
    const bool active = g < NGROUP;
    const int row0 = g * 16;
    float bn_s[2] = {0.f, 0.f};
    float bn_q[2] = {0.f, 0.f};
    const uint4* y4 = (const uint4*)y;
    _Float16* s_Ap = &s_A[p][0];
    _Float16* s_Tp = &s_T[p][0];

    if (active) {
        for (int mb = 0; mb < 8; mb += 4) {
            const int m0 = sub * 8 + mb;
            int e[4], en[4], s[4];
            float a[4][8];
            uint4 v[4];
            #pragma unroll
            for (int i = 0; i < 4; i++) {
                int row = row0 + m0 + i;
                e[i] = rowPtr[row] + gph;
                en[i] = rowPtr[row + 1];
                #pragma unroll
                for (int j = 0; j < 8; j++) a[i][j] = 0.0f;
            }
            if (gph == 0) {
                #pragma unroll
                for (int i = 0; i < 4; i++) {
                    uint4 sv = y4[(size_t)(row0 + m0 + i) * 8 + cc];
                    float f[8]; unpack8(sv, f);
                    #pragma unroll
                    for (int j = 0; j < 8; j++) a[i][j] = eps1 * f[j];
                }
            }
            #pragma unroll
            for (int i = 0; i < 4; i++) s[i] = (e[i] < en[i]) ? csr_src[e[i]] : -1;
            #pragma unroll
            for (int i = 0; i < 4; i++) if (s[i] >= 0) v[i] = y4[(size_t)s[i] * 8 + cc];

            int mx = max(max(s[0], s[1]), max(s[2], s[3]));
            while (mx >= 0) {
                int n[4]; uint4 pf[4];
                #pragma unroll
                for (int i = 0; i < 4; i++) {
                    n[i] = -1;
                    if (s[i] >= 0) { e[i] += 8; n[i] = (e[i] < en[i]) ? csr_src[e[i]] : -1; }
                }
                #pragma unroll
                for (int i = 0; i < 4; i++) if (n[i] >= 0) pf[i] = y4[(size_t)n[i] * 8 + cc];
                #pragma unroll
                for (int i = 0; i < 4; i++) {
                    if (s[i] >= 0) {
                        float f[8]; unpack8(v[i], f);
                        #pragma unroll
                        for (int j = 0; j < 8; j++) a[i][j] += f[j];
                    }
                    s[i] = n[i]; v[i] = pf[i];
                }
                mx = max(max(s[0], s[1]), max(s[2], s[3]));
            }

            #pragma unroll
            for (int off = 8; off < 64; off <<= 1)
                #pragma unroll
                for (int i = 0; i < 4; i++)
                    #pragma unroll
                    for (int j = 0; j < 8; j++)
                        a[i][j] += __shfl_xor(a[i][j], off, 64);

            if (gph == 0) {
                #pragma unroll
                for (int i = 0; i < 4; i++) {
                    half8 hv;
                    #pragma unroll
                    for (int j = 0; j < 8; j++)
                        hv[j] = (_Float16)fmaxf(a[i][j] + bav[j], 0.0f);
                    int slot = (cc >> 2) * 64 + (cc & 3) * 16 + (m0 + i);
                    *(half8*)(s_Ap + (size_t)aswz(slot) * 8) = hv;
                }
            }
        }
    }
    __syncthreads();   // pair's A tile complete

    if (active) {
        half8 af2[2];
        #pragma unroll
        for (int kc = 0; kc < 2; kc++)
            af2[kc] = *(const half8*)(s_Ap + (size_t)aswz(kc * 64 + lane) * 8);
        floatx4 acc2[2] = {};
        #pragma unroll
        for (int ntl = 0; ntl < 2; ntl++) {
            int nt = sub * 2 + ntl;
            #pragma unroll
            for (int kc = 0; kc < 2; kc++) {
                half8 bf = *(const half8*)(s_B2 + ((size_t)(kc * 4 + nt) * 64 + lane) * 8);
                acc2[ntl] = __builtin_amdgcn_mfma_f32_16x16x32_f16(af2[kc], bf, acc2[ntl], 0, 0, 0);
            }
        }
        // epilogue: bias + ReLU + BN partials into pair D tile (cols sub*32..sub*32+31)
        #pragma unroll
        for (int ntl = 0; ntl < 2; ntl++)
            #pragma unroll
            for (int r = 0; r < 4; r++) {
                float val = fmaxf(acc2[ntl][r] + bbv[ntl], 0.0f);
                bn_s[ntl] += val;
                bn_q[ntl] += val * val;
                s_Tp[(q * 4 + r) * 64 + (sub * 2 + ntl) * 16 + mm] = (_Float16)val;
            }
    }
    __syncthreads();   // pair's D tile complete

    if (active) {
        half8 t = *(const half8*)(s_Tp + sub * 512 + (size_t)lane * 8);
        ((half8*)((_Float16*)h_out + (size_t)g * 1024))[sub * 64 + lane] = t;
    }

    // BN stat reduction: shfl within wave -> s_red[w][32] -> 2 atomics/col/block
    #pragma unroll
    for (int ntl = 0; ntl < 2; ntl++) {
        bn_s[ntl] += __shfl_xor(bn_s[ntl], 16, 64);
        bn_s[ntl] += __shfl_xor(bn_s[ntl], 32, 64);
        bn_q[ntl] += __shfl_xor(bn_q[ntl], 16, 64);
        bn_q[ntl] += __shfl_xor(bn_q[ntl], 32, 64);
    }
    __syncthreads();
    if (lane < 16) {
        s_red[w][lane]      = bn_s[0];
        s_red[w][16 + lane] = bn_s[1];
    }
    __syncthreads();
    if (w == 0) {
        int sn = lane >> 5, lc = lane & 31;
        float s = 0;
        #pragma unroll
        for (int j = 0; j < 4; j++) s += s_red[2 * j + sn][lc];
        atomicAdd(&stats_out[lane], s);
    }
    __syncthreads();
    if (lane < 16) {
        s_red[w][lane]      = bn_q[0];
        s_red[w][16 + lane] = bn_q[1];
    }
    __syncthreads();
    if (w == 0) {
        int sn = lane >> 5, lc = lane & 31;
        float s = 0;
        #pragma unroll
        for (int j = 0; j < 4; j++) s += s_red[2 * j + sn][lc];
        atomicAdd(&stats_out[64 + lane], s);
    }
}

// ---------------- final: BN+ReLU of layer 3 (fp16 h), then (N,64)@(64,10)+b ----------------
__global__ __launch_bounds__(256) void final_linear_kernel(
    const ushort* __restrict__ h, const float* __restrict__ stats,
    const float* __restrict__ g, const float* __restrict__ be,
    const float* __restrict__ w, const float* __restrict__ b,
    float* __restrict__ out)
{
    __shared__ float s_w[640];
    __shared__ float s_b[10];
    __shared__ float s_scale[64];
    __shared__ float s_shift[64];
    for (int i = threadIdx.x; i < 640; i += 256) s_w[i] = w[i];
    if (threadIdx.x < 10) s_b[threadIdx.x] = b[threadIdx.x];
    if (threadIdx.x < 64) {
        int c = threadIdx.x;
        float mean = stats[c] * (1.0f / NN);
        float var  = stats[64 + c] * (1.0f / NN) - mean * mean;
        float rstd = rsqrtf(var + BN_EPS);
        float s    = rstd * g[c];
        s_scale[c] = s;
        s_shift[c] = be[c] - mean * s;
    }
    __syncthreads();
    int row = blockIdx.x * 256 + threadIdx.x;
    if (row >= NN) return;
    float acc[10];
    #pragma unroll
    for (int c = 0; c < 10; c++) acc[c] = s_b[c];
    const uint4* hr = (const uint4*)(h + (size_t)row * 64);
    #pragma unroll
    for (int ch = 0; ch < 8; ch++) {
        uint4 v = hr[ch];
        float f[8]; unpack8(v, f);
        #pragma unroll
        for (int j = 0; j < 8; j++) {
            int k = ch * 8 + j;
            float val = fmaxf(fmaf(f[j], s_scale[k], s_shift[k]), 0.0f);
            #pragma unroll
            for (int c = 0; c < 10; c++) acc[c] = fmaf(val, s_w[k * 10 + c], acc[c]);
        }
    }
    #pragma unroll
    for (int c = 0; c < 10; c++) out[row * 10 + c] = acc[c];
}

extern "C" void kernel_launch(void* const* d_in, const int* in_sizes, int n_in,
                              void* d_out, int out_size, void* d_ws, size_t ws_size,
                              hipStream_t stream)
{
    const float* x  = (const float*)d_in[0];
    const int*   ei = (const int*)d_in[1];
    const int E = in_sizes[1] / 2;

    const float* eps[3]; const float* wa[3]; const float* ba[3];
    const float* wb[3];  const float* bb[3]; const float* g[3]; const float* be[3];
    for (int i = 0; i < 3; i++) {
        int base = 2 + 7 * i;
        eps[i] = (const float*)d_in[base + 0];
        wa[i]  = (const float*)d_in[base + 1];
        ba[i]  = (const float*)d_in[base + 2];
        wb[i]  = (const float*)d_in[base + 3];
        bb[i]  = (const float*)d_in[base + 4];
        g[i]   = (const float*)d_in[base + 5];
        be[i]  = (const float*)d_in[base + 6];
    }
    const float* lin_w = (const float*)d_in[23];
    const float* lin_b = (const float*)d_in[24];
    float* out = (float*)d_out;

    // workspace layout
    char*  base   = (char*)d_ws;
    int*   gcur   = (int*)base;               // 512
    int*   rowPtr = gcur + 512;               // NN+1
    uint*  bucket = (uint*)(rowPtr + NN + 1); // NCHUNK*CHCAP
    int*   csrsrc = (int*)(bucket + (size_t)NCHUNK * CHCAP);  // E
    size_t ioff   = (char*)(csrsrc + E) - base;
    ushort* yb    = (ushort*)(base + ((ioff + 15) & ~(size_t)15));  // NN*64
    ushort* hA    = yb + (size_t)NN * 64;     // NN*64
    ushort* hB    = hA + (size_t)NN * 64;     // NN*64
    float* stats  = (float*)(hB + (size_t)NN * 64);  // 3*128

    // ---- CSR build (bucketed) ----
    hipMemsetAsync(gcur, 0, 512 * sizeof(int), stream);
    hipMemsetAsync(stats, 0, 3 * 128 * sizeof(float), stream);
    sortA_kernel<<<(E + SLAB - 1) / SLAB, 256, 0, stream>>>(ei, gcur, bucket, E);
    fillB_kernel<<<NCHUNK, 256, 0, stream>>>(bucket, gcur, rowPtr, csrsrc);

    const int PB = (NGROUP + 3) / 4;   // 782 proj blocks
    const int GB = (NGROUP + 3) / 4;   // 782 gather blocks (4 groups x wave-pair)

    // ---- layer 1: proj x (fp32,128) -> y; fused gather+MLP ----
    proj_kernel<128, false><<<PB, 256, 0, stream>>>(
        x, nullptr, nullptr, nullptr, wa[0], yb);
    gin_gather_kernel<<<GB, 512, 0, stream>>>(
        yb, rowPtr, csrsrc, eps[0], ba[0], wb[0], bb[0], hA, stats);
    // ---- layer 2 ----
    proj_kernel<64, true><<<PB, 256, 0, stream>>>(
        hA, stats, g[0], be[0], wa[1], yb);
    gin_gather_kernel<<<GB, 512, 0, stream>>>(
        yb, rowPtr, csrsrc, eps[1], ba[1], wb[1], bb[1], hB, stats + 128);
    // ---- layer 3 ----
    proj_kernel<64, true><<<PB, 256, 0, stream>>>(
        hB, stats + 128, g[1], be[1], wa[2], yb);
    gin_gather_kernel<<<GB, 512, 0, stream>>>(
        yb, rowPtr, csrsrc, eps[2], ba[2], wb[2], bb[2], hA, stats + 256);
    // ---- final ----
    final_linear_kernel<<<(NN + 255) / 256, 256, 0, stream>>>(
        hA, stats + 256, g[2], be[2], lin_w, lin_b, out);
}

// Round 12
// 339.856 us; speedup vs baseline: 1.4820x; 1.4820x over previous
//
#include <hip/hip_runtime.h>
#include <hip/hip_fp16.h>

#define NN 50000
#define NGROUP 3125   // NN / 16 (exact)
#define NCHUNK 391    // ceil(NN / 128)
#define CHCAP 3072    // bucket capacity per chunk (expected ~2046)
#define SLAB 2048
#define BN_EPS 1e-5f

typedef unsigned int uint;
typedef unsigned short ushort;
typedef _Float16 half8 __attribute__((ext_vector_type(8)));
typedef float floatx4 __attribute__((ext_vector_type(4)));

__device__ __forceinline__ int aswz(int slot) { return slot ^ ((slot >> 4) & 7); }

__device__ __forceinline__ float h_lo(uint u) {
    return __half2float(__ushort_as_half((ushort)(u & 0xFFFFu)));
}
__device__ __forceinline__ float h_hi(uint u) {
    return __half2float(__ushort_as_half((ushort)(u >> 16)));
}
__device__ __forceinline__ void unpack8(uint4 v, float* f) {
    f[0] = h_lo(v.x); f[1] = h_hi(v.x);
    f[2] = h_lo(v.y); f[3] = h_hi(v.y);
    f[4] = h_lo(v.z); f[5] = h_hi(v.z);
    f[6] = h_lo(v.w); f[7] = h_hi(v.w);
}

// ================= CSR build: LDS-sorted buckets, chunk-local fills =================
__global__ __launch_bounds__(256) void sortA_kernel(
    const int* __restrict__ ei, int* __restrict__ gcur,
    uint* __restrict__ bucket, int E)
{
    __shared__ int s_hist[NCHUNK];
    __shared__ int s_offs[NCHUNK];
    __shared__ int s_cur[NCHUNK];
    __shared__ int s_gb[NCHUNK];
    __shared__ int s_scanA[512], s_scanB[512];
    __shared__ uint s_sorted[SLAB];

    const int tid  = threadIdx.x;
    const int base = blockIdx.x * SLAB;
    const int cnt  = min(SLAB, E - base);

    for (int i = tid; i < NCHUNK; i += 256) s_hist[i] = 0;
    __syncthreads();

    uint pk[SLAB / 256];
    int nloc = 0;
    for (int i = tid; i < cnt; i += 256) {
        int src = ei[base + i];
        int dst = ei[E + base + i];
        int c = dst >> 7;
        pk[nloc++] = (uint)src | ((uint)(dst & 127) << 16) | ((uint)c << 23);
        atomicAdd(&s_hist[c], 1);
    }
    __syncthreads();
    for (int i = tid; i < 512; i += 256) s_scanA[i] = (i < NCHUNK) ? s_hist[i] : 0;
    __syncthreads();
    int* sa = s_scanA; int* sb = s_scanB;
    for (int off = 1; off < 512; off <<= 1) {
        for (int i = tid; i < 512; i += 256)
            sb[i] = sa[i] + ((i >= off) ? sa[i - off] : 0);
        __syncthreads();
        int* t = sa; sa = sb; sb = t;
    }
    for (int i = tid; i < NCHUNK; i += 256) {
        int excl = sa[i] - s_hist[i];
        s_offs[i] = excl;
        s_cur[i]  = excl;
    }
    __syncthreads();
    for (int k = 0; k < nloc; k++) {
        int c = pk[k] >> 23;
        int pos = atomicAdd(&s_cur[c], 1);
        s_sorted[pos] = pk[k];
    }
    __syncthreads();
    for (int c = tid; c < NCHUNK; c += 256) {
        int n = s_hist[c];
        s_gb[c] = n ? atomicAdd(&gcur[c], n) : 0;
    }
    __syncthreads();
    for (int i = tid; i < cnt; i += 256) {
        uint v = s_sorted[i];
        int c = v >> 23;
        int li = i - s_offs[c];
        bucket[(size_t)c * CHCAP + s_gb[c] + li] = v;
    }
}

// phase B: one block per chunk — inline base scan + per-row hist/scan -> rowPtr + dense fill.
__global__ __launch_bounds__(256) void fillB_kernel(
    const uint* __restrict__ bucket, const int* __restrict__ gcur,
    int* __restrict__ rowPtr, int* __restrict__ csr_src)
{
    __shared__ int s_hist[128];
    __shared__ int s_excl[128];
    __shared__ int s_cur[128];
    __shared__ int s_ws[4];
    __shared__ int s_base;
    const int c = blockIdx.x;
    const int tid = threadIdx.x;
    const int cnt = gcur[c];
    const int row0 = c * 128;

    int part = 0;
    for (int i = tid; i < c; i += 256) part += gcur[i];
    #pragma unroll
    for (int off = 32; off >= 1; off >>= 1) part += __shfl_down(part, off, 64);
    if ((tid & 63) == 0) s_ws[tid >> 6] = part;
    if (tid < 128) s_hist[tid] = 0;
    __syncthreads();
    if (tid == 0) s_base = s_ws[0] + s_ws[1] + s_ws[2] + s_ws[3];
    __syncthreads();
    const int base = s_base;
    if (tid == 0 && c == NCHUNK - 1) rowPtr[NN] = base + cnt;

    for (int i = tid; i < cnt; i += 256) {
        uint v = bucket[(size_t)c * CHCAP + i];
        atomicAdd(&s_hist[(v >> 16) & 127], 1);
    }
    __syncthreads();
    if (tid < 128) {
        int lane = tid & 63;
        int v = s_hist[tid];
        int incl = v;
        #pragma unroll
        for (int off = 1; off < 64; off <<= 1) {
            int t = __shfl_up(incl, off, 64);
            if (lane >= off) incl += t;
        }
        s_excl[tid] = incl - v;
    }
    __syncthreads();
    if (tid < 128) {
        int excl = s_excl[tid];
        if (tid >= 64) excl += s_excl[63] + s_hist[63];
        s_cur[tid] = excl;
        int row = row0 + tid;
        if (row < NN) rowPtr[row] = base + excl;
    }
    __syncthreads();
    for (int i = tid; i < cnt; i += 256) {
        uint v = bucket[(size_t)c * CHCAP + i];
        int dl  = (v >> 16) & 127;
        int src = v & 0xFFFFu;
        int ofs = atomicAdd(&s_cur[dl], 1);
        csr_src[base + ofs] = src;
    }
}

// ======== proj: y = W_a^T * z, z = BNReLU(h_in) [APPLY] or cvt(x) [layer 1] ========
template<int FIN, bool APPLY>
__global__ __launch_bounds__(256, 4) void proj_kernel(
    const void* __restrict__ in_v,
    const float* __restrict__ stats_in, const float* __restrict__ g_in,
    const float* __restrict__ be_in,
    const float* __restrict__ wa,
    ushort* __restrict__ y_out)
{
    constexpr int KC = FIN / 32;
    __shared__ __align__(16) _Float16 s_B[FIN * 64];
    __shared__ __align__(16) _Float16 s_Y[4][1024];

    const int tid = threadIdx.x, w = tid >> 6, lane = tid & 63;
    const int q = lane >> 4, mm = lane & 15;

    for (int i = tid; i < FIN * 64; i += 256) {
        int j = i & 7, l = (i >> 3) & 63, t = i >> 9;
        int kc = t >> 2, nt = t & 3;
        int k = kc * 32 + (l >> 4) * 8 + j;
        int n = nt * 16 + (l & 15);
        s_B[i] = (_Float16)wa[k * 64 + n];
    }

    float scv[2][8], shv[2][8];
    if (APPLY) {
        #pragma unroll
        for (int kc = 0; kc < 2; kc++)
            #pragma unroll
            for (int j = 0; j < 8; j++) {
                int c = kc * 32 + q * 8 + j;
                float mean = stats_in[c] * (1.0f / NN);
                float var  = stats_in[64 + c] * (1.0f / NN) - mean * mean;
                float rstd = rsqrtf(var + BN_EPS);
                float s    = rstd * g_in[c];
                scv[kc][j] = s;
                shv[kc][j] = be_in[c] - mean * s;
            }
    }
    __syncthreads();

    int g = blockIdx.x * 4 + w;
    if (g >= NGROUP) return;
    const int row = g * 16 + mm;

    half8 af[KC];
    if (FIN == 128) {
        const float* xin = (const float*)in_v;
        #pragma unroll
        for (int kc = 0; kc < KC; kc++) {
            const float* p = xin + (size_t)row * 128 + kc * 32 + q * 8;
            float4 a = *(const float4*)p;
            float4 b = *(const float4*)(p + 4);
            half8 hv;
            hv[0] = (_Float16)a.x; hv[1] = (_Float16)a.y;
            hv[2] = (_Float16)a.z; hv[3] = (_Float16)a.w;
            hv[4] = (_Float16)b.x; hv[5] = (_Float16)b.y;
            hv[6] = (_Float16)b.z; hv[7] = (_Float16)b.w;
            af[kc] = hv;
        }
    } else {
        const ushort* hin = (const ushort*)in_v;
        #pragma unroll
        for (int kc = 0; kc < KC; kc++) {
            uint4 vv = *(const uint4*)(hin + (size_t)row * 64 + kc * 32 + q * 8);
            float f[8]; unpack8(vv, f);
            half8 hv;
            #pragma unroll
            for (int j = 0; j < 8; j++) {
                float z = APPLY ? fmaxf(fmaf(f[j], scv[kc][j], shv[kc][j]), 0.0f) : f[j];
                hv[j] = (_Float16)z;
            }
            af[kc] = hv;
        }
    }

    floatx4 acc[4] = {};
    #pragma unroll
    for (int nt = 0; nt < 4; nt++)
        #pragma unroll
        for (int kc = 0; kc < KC; kc++) {
            half8 bf = *(const half8*)(s_B + ((size_t)(kc * 4 + nt) * 64 + lane) * 8);
            acc[nt] = __builtin_amdgcn_mfma_f32_16x16x32_f16(af[kc], bf, acc[nt], 0, 0, 0);
        }

    _Float16* s_Yw = &s_Y[w][0];
    #pragma unroll
    for (int nt = 0; nt < 4; nt++)
        #pragma unroll
        for (int r = 0; r < 4; r++)
            s_Yw[(q * 4 + r) * 64 + nt * 16 + mm] = (_Float16)acc[nt][r];
    half8 t0 = *(const half8*)(s_Yw + lane * 8);
    half8 t1 = *(const half8*)(s_Yw + 512 + lane * 8);
    half8* dst = (half8*)((_Float16*)y_out + (size_t)g * 1024);
    dst[lane] = t0;
    dst[64 + lane] = t1;
}

// ======== gather: wave-PAIR per 16-row group; (512,4) => spill-free regs + 25.6 KB LDS ========
__global__ __launch_bounds__(512, 4) void gin_gather_kernel(
    const ushort* __restrict__ y,
    const int* __restrict__ rowPtr, const int* __restrict__ csr_src,
    const float* __restrict__ eps_p, const float* __restrict__ ba,
    const float* __restrict__ wb, const float* __restrict__ bb,
    ushort* __restrict__ h_out, float* __restrict__ stats_out)
{
    __shared__ __align__(16) _Float16 s_B2[64 * 64];
    __shared__ __align__(16) _Float16 s_A[4][1024];   // pair-shared A fragments
    __shared__ __align__(16) _Float16 s_T[4][1024];   // pair-shared D tile
    __shared__ float s_red[8][32];

    const int tid = threadIdx.x, w = tid >> 6, lane = tid & 63;
    const int p = w >> 1, sub = w & 1;
    const int cc = lane & 7, gph = lane >> 3;
    const int q = lane >> 4, mm = lane & 15;

    for (int i = tid; i < 64 * 64; i += 512) {
        int j = i & 7, l = (i >> 3) & 63, t = i >> 9;
        int kc = t >> 2, nt = t & 3;
        int k = kc * 32 + (l >> 4) * 8 + j;
        int n = nt * 16 + (l & 15);
        s_B2[i] = (_Float16)wb[k * 64 + n];
    }

    const float eps1 = 1.0f + eps_p[0];
    float bav[8];
    #pragma unroll
    for (int j = 0; j < 8; j++) bav[j] = ba[8 * cc + j];
    float bbv[2];
    #pragma unroll
    for (int ntl = 0; ntl < 2; ntl++) bbv[ntl] = bb[(sub * 2 + ntl) * 16 + mm];
    __syncthreads();

    const int g = blockIdx.x * 4 + p;
    const bool active = g < NGROUP;
    const int row0 = g * 16;
    float bn_s[2] = {0.f, 0.f};
    float bn_q[2] = {0.f, 0.f};
    const uint4* y4 = (const uint4*)y;
    _Float16* s_Ap = &s_A[p][0];
    _Float16* s_Tp = &s_T[p][0];

    if (active) {
        for (int mb = 0; mb < 8; mb += 4) {
            const int m0 = sub * 8 + mb;
            int e[4], en[4], s[4];
            float a[4][8];
            uint4 v[4];
            #pragma unroll
            for (int i = 0; i < 4; i++) {
                int row = row0 + m0 + i;
                e[i] = rowPtr[row] + gph;
                en[i] = rowPtr[row + 1];
                #pragma unroll
                for (int j = 0; j < 8; j++) a[i][j] = 0.0f;
            }
            if (gph == 0) {
                #pragma unroll
                for (int i = 0; i < 4; i++) {
                    uint4 sv = y4[(size_t)(row0 + m0 + i) * 8 + cc];
                    float f[8]; unpack8(sv, f);
                    #pragma unroll
                    for (int j = 0; j < 8; j++) a[i][j] = eps1 * f[j];
                }
            }
            #pragma unroll
            for (int i = 0; i < 4; i++) s[i] = (e[i] < en[i]) ? csr_src[e[i]] : -1;
            #pragma unroll
            for (int i = 0; i < 4; i++) if (s[i] >= 0) v[i] = y4[(size_t)s[i] * 8 + cc];

            int mx = max(max(s[0], s[1]), max(s[2], s[3]));
            while (mx >= 0) {
                int n[4]; uint4 pf[4];
                #pragma unroll
                for (int i = 0; i < 4; i++) {
                    n[i] = -1;
                    if (s[i] >= 0) { e[i] += 8; n[i] = (e[i] < en[i]) ? csr_src[e[i]] : -1; }
                }
                #pragma unroll
                for (int i = 0; i < 4; i++) if (n[i] >= 0) pf[i] = y4[(size_t)n[i] * 8 + cc];
                #pragma unroll
                for (int i = 0; i < 4; i++) {
                    if (s[i] >= 0) {
                        float f[8]; unpack8(v[i], f);
                        #pragma unroll
                        for (int j = 0; j < 8; j++) a[i][j] += f[j];
                    }
                    s[i] = n[i]; v[i] = pf[i];
                }
                mx = max(max(s[0], s[1]), max(s[2], s[3]));
            }

            #pragma unroll
            for (int off = 8; off < 64; off <<= 1)
                #pragma unroll
                for (int i = 0; i < 4; i++)
                    #pragma unroll
                    for (int j = 0; j < 8; j++)
                        a[i][j] += __shfl_xor(a[i][j], off, 64);

            if (gph == 0) {
                #pragma unroll
                for (int i = 0; i < 4; i++) {
                    half8 hv;
                    #pragma unroll
                    for (int j = 0; j < 8; j++)
                        hv[j] = (_Float16)fmaxf(a[i][j] + bav[j], 0.0f);
                    int slot = (cc >> 2) * 64 + (cc & 3) * 16 + (m0 + i);
                    *(half8*)(s_Ap + (size_t)aswz(slot) * 8) = hv;
                }
            }
        }
    }
    __syncthreads();   // pair's A tile complete

    if (active) {
        half8 af2[2];
        #pragma unroll
        for (int kc = 0; kc < 2; kc++)
            af2[kc] = *(const half8*)(s_Ap + (size_t)aswz(kc * 64 + lane) * 8);
        floatx4 acc2[2] = {};
        #pragma unroll
        for (int ntl = 0; ntl < 2; ntl++) {
            int nt = sub * 2 + ntl;
            #pragma unroll
            for (int kc = 0; kc < 2; kc++) {
                half8 bf = *(const half8*)(s_B2 + ((size_t)(kc * 4 + nt) * 64 + lane) * 8);
                acc2[ntl] = __builtin_amdgcn_mfma_f32_16x16x32_f16(af2[kc], bf, acc2[ntl], 0, 0, 0);
            }
        }
        #pragma unroll
        for (int ntl = 0; ntl < 2; ntl++)
            #pragma unroll
            for (int r = 0; r < 4; r++) {
                float val = fmaxf(acc2[ntl][r] + bbv[ntl], 0.0f);
                bn_s[ntl] += val;
                bn_q[ntl] += val * val;
                s_Tp[(q * 4 + r) * 64 + (sub * 2 + ntl) * 16 + mm] = (_Float16)val;
            }
    }
    __syncthreads();   // pair's D tile complete

    if (active) {
        half8 t = *(const half8*)(s_Tp + sub * 512 + (size_t)lane * 8);
        ((half8*)((_Float16*)h_out + (size_t)g * 1024))[sub * 64 + lane] = t;
    }

    // BN stat reduction
    #pragma unroll
    for (int ntl = 0; ntl < 2; ntl++) {
        bn_s[ntl] += __shfl_xor(bn_s[ntl], 16, 64);
        bn_s[ntl] += __shfl_xor(bn_s[ntl], 32, 64);
        bn_q[ntl] += __shfl_xor(bn_q[ntl], 16, 64);
        bn_q[ntl] += __shfl_xor(bn_q[ntl], 32, 64);
    }
    __syncthreads();
    if (lane < 16) {
        s_red[w][lane]      = bn_s[0];
        s_red[w][16 + lane] = bn_s[1];
    }
    __syncthreads();
    if (w == 0) {
        int sn = lane >> 5, lc = lane & 31;
        float s = 0;
        #pragma unroll
        for (int j = 0; j < 4; j++) s += s_red[2 * j + sn][lc];
        atomicAdd(&stats_out[lane], s);
    }
    __syncthreads();
    if (lane < 16) {
        s_red[w][lane]      = bn_q[0];
        s_red[w][16 + lane] = bn_q[1];
    }
    __syncthreads();
    if (w == 0) {
        int sn = lane >> 5, lc = lane & 31;
        float s = 0;
        #pragma unroll
        for (int j = 0; j < 4; j++) s += s_red[2 * j + sn][lc];
        atomicAdd(&stats_out[64 + lane], s);
    }
}

// ---------------- final: BN+ReLU of layer 3 (fp16 h), then (N,64)@(64,10)+b ----------------
__global__ __launch_bounds__(256) void final_linear_kernel(
    const ushort* __restrict__ h, const float* __restrict__ stats,
    const float* __restrict__ g, const float* __restrict__ be,
    const float* __restrict__ w, const float* __restrict__ b,
    float* __restrict__ out)
{
    __shared__ float s_w[640];
    __shared__ float s_b[10];
    __shared__ float s_scale[64];
    __shared__ float s_shift[64];
    for (int i = threadIdx.x; i < 640; i += 256) s_w[i] = w[i];
    if (threadIdx.x < 10) s_b[threadIdx.x] = b[threadIdx.x];
    if (threadIdx.x < 64) {
        int c = threadIdx.x;
        float mean = stats[c] * (1.0f / NN);
        float var  = stats[64 + c] * (1.0f / NN) - mean * mean;
        float rstd = rsqrtf(var + BN_EPS);
        float s    = rstd * g[c];
        s_scale[c] = s;
        s_shift[c] = be[c] - mean * s;
    }
    __syncthreads();
    int row = blockIdx.x * 256 + threadIdx.x;
    if (row >= NN) return;
    float acc[10];
    #pragma unroll
    for (int c = 0; c < 10; c++) acc[c] = s_b[c];
    const uint4* hr = (const uint4*)(h + (size_t)row * 64);
    #pragma unroll
    for (int ch = 0; ch < 8; ch++) {
        uint4 v = hr[ch];
        float f[8]; unpack8(v, f);
        #pragma unroll
        for (int j = 0; j < 8; j++) {
            int k = ch * 8 + j;
            float val = fmaxf(fmaf(f[j], s_scale[k], s_shift[k]), 0.0f);
            #pragma unroll
            for (int c = 0; c < 10; c++) acc[c] = fmaf(val, s_w[k * 10 + c], acc[c]);
        }
    }
    #pragma unroll
    for (int c = 0; c < 10; c++) out[row * 10 + c] = acc[c];
}

extern "C" void kernel_launch(void* const* d_in, const int* in_sizes, int n_in,
                              void* d_out, int out_size, void* d_ws, size_t ws_size,
                              hipStream_t stream)
{
    const float* x  = (const float*)d_in[0];
    const int*   ei = (const int*)d_in[1];
    const int E = in_sizes[1] / 2;

    const float* eps[3]; const float* wa[3]; const float* ba[3];
    const float* wb[3];  const float* bb[3]; const float* g[3]; const float* be[3];
    for (int i = 0; i < 3; i++) {
        int base = 2 + 7 * i;
        eps[i] = (const float*)d_in[base + 0];
        wa[i]  = (const float*)d_in[base + 1];
        ba[i]  = (const float*)d_in[base + 2];
        wb[i]  = (const float*)d_in[base + 3];
        bb[i]  = (const float*)d_in[base + 4];
        g[i]   = (const float*)d_in[base + 5];
        be[i]  = (const float*)d_in[base + 6];
    }
    const float* lin_w = (const float*)d_in[23];
    const float* lin_b = (const float*)d_in[24];
    float* out = (float*)d_out;

    // workspace layout
    char*  base   = (char*)d_ws;
    int*   gcur   = (int*)base;               // 512
    int*   rowPtr = gcur + 512;               // NN+1
    uint*  bucket = (uint*)(rowPtr + NN + 1); // NCHUNK*CHCAP
    int*   csrsrc = (int*)(bucket + (size_t)NCHUNK * CHCAP);  // E
    size_t ioff   = (char*)(csrsrc + E) - base;
    ushort* yb    = (ushort*)(base + ((ioff + 15) & ~(size_t)15));  // NN*64
    ushort* hA    = yb + (size_t)NN * 64;     // NN*64
    ushort* hB    = hA + (size_t)NN * 64;     // NN*64
    float* stats  = (float*)(hB + (size_t)NN * 64);  // 3*128

    // ---- CSR build (bucketed) ----
    hipMemsetAsync(gcur, 0, 512 * sizeof(int), stream);
    hipMemsetAsync(stats, 0, 3 * 128 * sizeof(float), stream);
    sortA_kernel<<<(E + SLAB - 1) / SLAB, 256, 0, stream>>>(ei, gcur, bucket, E);
    fillB_kernel<<<NCHUNK, 256, 0, stream>>>(bucket, gcur, rowPtr, csrsrc);

    const int PB = (NGROUP + 3) / 4;   // 782 proj blocks
    const int GB = (NGROUP + 3) / 4;   // 782 gather blocks (4 groups x wave-pair)

    // ---- layer 1: proj x (fp32,128) -> y; fused gather+MLP ----
    proj_kernel<128, false><<<PB, 256, 0, stream>>>(
        x, nullptr, nullptr, nullptr, wa[0], yb);
    gin_gather_kernel<<<GB, 512, 0, stream>>>(
        yb, rowPtr, csrsrc, eps[0], ba[0], wb[0], bb[0], hA, stats);
    // ---- layer 2 ----
    proj_kernel<64, true><<<PB, 256, 0, stream>>>(
        hA, stats, g[0], be[0], wa[1], yb);
    gin_gather_kernel<<<GB, 512, 0, stream>>>(
        yb, rowPtr, csrsrc, eps[1], ba[1], wb[1], bb[1], hB, stats + 128);
    // ---- layer 3 ----
    proj_kernel<64, true><<<PB, 256, 0, stream>>>(
        hB, stats + 128, g[1], be[1], wa[2], yb);
    gin_gather_kernel<<<GB, 512, 0, stream>>>(
        yb, rowPtr, csrsrc, eps[2], ba[2], wb[2], bb[2], hA, stats + 256);
    // ---- final ----
    final_linear_kernel<<<(NN + 255) / 256, 256, 0, stream>>>(
        hA, stats + 256, g[2], be[2], lin_w, lin_b, out);
}

// Round 13
// 299.151 us; speedup vs baseline: 1.6836x; 1.1361x over previous
//
#include <hip/hip_runtime.h>
#include <hip/hip_fp16.h>

#define NN 50000
#define NGROUP 3125   // NN / 16 (exact)
#define NCHUNK 391    // ceil(NN / 128)
#define CHCAP 3072    // bucket capacity per chunk (expected ~2046)
#define SLAB 8192
#define BN_EPS 1e-5f

typedef unsigned int uint;
typedef unsigned short ushort;
typedef _Float16 half8 __attribute__((ext_vector_type(8)));
typedef float floatx4 __attribute__((ext_vector_type(4)));

__device__ __forceinline__ int aswz(int slot) { return slot ^ ((slot >> 4) & 7); }

__device__ __forceinline__ float h_lo(uint u) {
    return __half2float(__ushort_as_half((ushort)(u & 0xFFFFu)));
}
__device__ __forceinline__ float h_hi(uint u) {
    return __half2float(__ushort_as_half((ushort)(u >> 16)));
}
__device__ __forceinline__ void unpack8(uint4 v, float* f) {
    f[0] = h_lo(v.x); f[1] = h_hi(v.x);
    f[2] = h_lo(v.y); f[3] = h_hi(v.y);
    f[4] = h_lo(v.z); f[5] = h_hi(v.z);
    f[6] = h_lo(v.w); f[7] = h_hi(v.w);
}

// ================= CSR build: LDS-sorted buckets, chunk-local fills =================
__global__ __launch_bounds__(256) void sortA_kernel(
    const int* __restrict__ ei, int* __restrict__ gcur,
    uint* __restrict__ bucket, int E)
{
    __shared__ int s_hist[NCHUNK];
    __shared__ int s_offs[NCHUNK];
    __shared__ int s_cur[NCHUNK];
    __shared__ int s_gb[NCHUNK];
    __shared__ int s_scanA[512], s_scanB[512];
    __shared__ uint s_sorted[SLAB];

    const int tid  = threadIdx.x;
    const int base = blockIdx.x * SLAB;
    const int cnt  = min(SLAB, E - base);

    for (int i = tid; i < NCHUNK; i += 256) s_hist[i] = 0;
    __syncthreads();

    uint pk[SLAB / 256];
    int nloc = 0;
    for (int i = tid; i < cnt; i += 256) {
        int src = ei[base + i];
        int dst = ei[E + base + i];
        int c = dst >> 7;
        pk[nloc++] = (uint)src | ((uint)(dst & 127) << 16) | ((uint)c << 23);
        atomicAdd(&s_hist[c], 1);
    }
    __syncthreads();
    for (int i = tid; i < 512; i += 256) s_scanA[i] = (i < NCHUNK) ? s_hist[i] : 0;
    __syncthreads();
    int* sa = s_scanA; int* sb = s_scanB;
    for (int off = 1; off < 512; off <<= 1) {
        for (int i = tid; i < 512; i += 256)
            sb[i] = sa[i] + ((i >= off) ? sa[i - off] : 0);
        __syncthreads();
        int* t = sa; sa = sb; sb = t;
    }
    for (int i = tid; i < NCHUNK; i += 256) {
        int excl = sa[i] - s_hist[i];
        s_offs[i] = excl;
        s_cur[i]  = excl;
    }
    __syncthreads();
    for (int k = 0; k < nloc; k++) {
        int c = pk[k] >> 23;
        int pos = atomicAdd(&s_cur[c], 1);
        s_sorted[pos] = pk[k];
    }
    __syncthreads();
    for (int c = tid; c < NCHUNK; c += 256) {
        int n = s_hist[c];
        s_gb[c] = n ? atomicAdd(&gcur[c], n) : 0;
    }
    __syncthreads();
    for (int i = tid; i < cnt; i += 256) {
        uint v = s_sorted[i];
        int c = v >> 23;
        int li = i - s_offs[c];
        bucket[(size_t)c * CHCAP + s_gb[c] + li] = v;
    }
}

// phase B: one block per chunk — inline base scan + per-row hist/scan -> rowPtr + dense fill.
__global__ __launch_bounds__(256) void fillB_kernel(
    const uint* __restrict__ bucket, const int* __restrict__ gcur,
    int* __restrict__ rowPtr, int* __restrict__ csr_src)
{
    __shared__ int s_hist[128];
    __shared__ int s_excl[128];
    __shared__ int s_cur[128];
    __shared__ int s_ws[4];
    __shared__ int s_base;
    const int c = blockIdx.x;
    const int tid = threadIdx.x;
    const int cnt = gcur[c];
    const int row0 = c * 128;

    int part = 0;
    for (int i = tid; i < c; i += 256) part += gcur[i];
    #pragma unroll
    for (int off = 32; off >= 1; off >>= 1) part += __shfl_down(part, off, 64);
    if ((tid & 63) == 0) s_ws[tid >> 6] = part;
    if (tid < 128) s_hist[tid] = 0;
    __syncthreads();
    if (tid == 0) s_base = s_ws[0] + s_ws[1] + s_ws[2] + s_ws[3];
    __syncthreads();
    const int base = s_base;
    if (tid == 0 && c == NCHUNK - 1) rowPtr[NN] = base + cnt;

    for (int i = tid; i < cnt; i += 256) {
        uint v = bucket[(size_t)c * CHCAP + i];
        atomicAdd(&s_hist[(v >> 16) & 127], 1);
    }
    __syncthreads();
    if (tid < 128) {
        int lane = tid & 63;
        int v = s_hist[tid];
        int incl = v;
        #pragma unroll
        for (int off = 1; off < 64; off <<= 1) {
            int t = __shfl_up(incl, off, 64);
            if (lane >= off) incl += t;
        }
        s_excl[tid] = incl - v;
    }
    __syncthreads();
    if (tid < 128) {
        int excl = s_excl[tid];
        if (tid >= 64) excl += s_excl[63] + s_hist[63];
        s_cur[tid] = excl;
        int row = row0 + tid;
        if (row < NN) rowPtr[row] = base + excl;
    }
    __syncthreads();
    for (int i = tid; i < cnt; i += 256) {
        uint v = bucket[(size_t)c * CHCAP + i];
        int dl  = (v >> 16) & 127;
        int src = v & 0xFFFFu;
        int ofs = atomicAdd(&s_cur[dl], 1);
        csr_src[base + ofs] = src;
    }
}

// ======== proj: y = W_a^T * z, z = BNReLU(h_in) [APPLY] or cvt(x) [layer 1] ========
template<int FIN, bool APPLY>
__global__ __launch_bounds__(256, 4) void proj_kernel(
    const void* __restrict__ in_v,
    const float* __restrict__ stats_in, const float* __restrict__ g_in,
    const float* __restrict__ be_in,
    const float* __restrict__ wa,
    ushort* __restrict__ y_out)
{
    constexpr int KC = FIN / 32;
    __shared__ __align__(16) _Float16 s_B[FIN * 64];
    __shared__ __align__(16) _Float16 s_Y[4][1024];

    const int tid = threadIdx.x, w = tid >> 6, lane = tid & 63;
    const int q = lane >> 4, mm = lane & 15;

    for (int i = tid; i < FIN * 64; i += 256) {
        int j = i & 7, l = (i >> 3) & 63, t = i >> 9;
        int kc = t >> 2, nt = t & 3;
        int k = kc * 32 + (l >> 4) * 8 + j;
        int n = nt * 16 + (l & 15);
        s_B[i] = (_Float16)wa[k * 64 + n];
    }

    float scv[2][8], shv[2][8];
    if (APPLY) {
        #pragma unroll
        for (int kc = 0; kc < 2; kc++)
            #pragma unroll
            for (int j = 0; j < 8; j++) {
                int c = kc * 32 + q * 8 + j;
                float mean = stats_in[c] * (1.0f / NN);
                float var  = stats_in[64 + c] * (1.0f / NN) - mean * mean;
                float rstd = rsqrtf(var + BN_EPS);
                float s    = rstd * g_in[c];
                scv[kc][j] = s;
                shv[kc][j] = be_in[c] - mean * s;
            }
    }
    __syncthreads();

    int g = blockIdx.x * 4 + w;
    if (g >= NGROUP) return;
    const int row = g * 16 + mm;

    half8 af[KC];
    if (FIN == 128) {
        const float* xin = (const float*)in_v;
        #pragma unroll
        for (int kc = 0; kc < KC; kc++) {
            const float* p = xin + (size_t)row * 128 + kc * 32 + q * 8;
            float4 a = *(const float4*)p;
            float4 b = *(const float4*)(p + 4);
            half8 hv;
            hv[0] = (_Float16)a.x; hv[1] = (_Float16)a.y;
            hv[2] = (_Float16)a.z; hv[3] = (_Float16)a.w;
            hv[4] = (_Float16)b.x; hv[5] = (_Float16)b.y;
            hv[6] = (_Float16)b.z; hv[7] = (_Float16)b.w;
            af[kc] = hv;
        }
    } else {
        const ushort* hin = (const ushort*)in_v;
        #pragma unroll
        for (int kc = 0; kc < KC; kc++) {
            uint4 vv = *(const uint4*)(hin + (size_t)row * 64 + kc * 32 + q * 8);
            float f[8]; unpack8(vv, f);
            half8 hv;
            #pragma unroll
            for (int j = 0; j < 8; j++) {
                float z = APPLY ? fmaxf(fmaf(f[j], scv[kc][j], shv[kc][j]), 0.0f) : f[j];
                hv[j] = (_Float16)z;
            }
            af[kc] = hv;
        }
    }

    floatx4 acc[4] = {};
    #pragma unroll
    for (int nt = 0; nt < 4; nt++)
        #pragma unroll
        for (int kc = 0; kc < KC; kc++) {
            half8 bf = *(const half8*)(s_B + ((size_t)(kc * 4 + nt) * 64 + lane) * 8);
            acc[nt] = __builtin_amdgcn_mfma_f32_16x16x32_f16(af[kc], bf, acc[nt], 0, 0, 0);
        }

    _Float16* s_Yw = &s_Y[w][0];
    #pragma unroll
    for (int nt = 0; nt < 4; nt++)
        #pragma unroll
        for (int r = 0; r < 4; r++)
            s_Yw[(q * 4 + r) * 64 + nt * 16 + mm] = (_Float16)acc[nt][r];
    half8 t0 = *(const half8*)(s_Yw + lane * 8);
    half8 t1 = *(const half8*)(s_Yw + 512 + lane * 8);
    half8* dst = (half8*)((_Float16*)y_out + (size_t)g * 1024);
    dst[lane] = t0;
    dst[64 + lane] = t1;
}

// ======== gather (round-10 proven): 1 wave per 16-row group; 4-row interleaved
// value-prefetched gather; GEMM2 + epilogue per wave; no cross-wave coupling. ========
__global__ __launch_bounds__(512, 4) void gin_gather_kernel(
    const ushort* __restrict__ y,
    const int* __restrict__ rowPtr, const int* __restrict__ csr_src,
    const float* __restrict__ eps_p, const float* __restrict__ ba,
    const float* __restrict__ wb, const float* __restrict__ bb,
    ushort* __restrict__ h_out, float* __restrict__ stats_out)
{
    __shared__ __align__(16) _Float16 s_B2[64 * 64];
    __shared__ __align__(16) _Float16 s_A[8][1024];
    __shared__ float s_red[8][64];

    const int tid = threadIdx.x, w = tid >> 6, lane = tid & 63;
    const int cc = lane & 7, gph = lane >> 3;
    const int q = lane >> 4, mm = lane & 15;

    for (int i = tid; i < 64 * 64; i += 512) {
        int j = i & 7, l = (i >> 3) & 63, t = i >> 9;
        int kc = t >> 2, nt = t & 3;
        int k = kc * 32 + (l >> 4) * 8 + j;
        int n = nt * 16 + (l & 15);
        s_B2[i] = (_Float16)wb[k * 64 + n];
    }

    const float eps1 = 1.0f + eps_p[0];
    float bav[8];
    #pragma unroll
    for (int j = 0; j < 8; j++) bav[j] = ba[8 * cc + j];
    float bbv[4];
    #pragma unroll
    for (int nt = 0; nt < 4; nt++) bbv[nt] = bb[nt * 16 + mm];
    __syncthreads();

    float bn_s[4] = {0.f, 0.f, 0.f, 0.f};
    float bn_q[4] = {0.f, 0.f, 0.f, 0.f};
    const uint4* y4 = (const uint4*)y;
    const int g = blockIdx.x * 8 + w;

    if (g < NGROUP) {
        const int row0 = g * 16;
        _Float16* s_Aw = &s_A[w][0];

        for (int m = 0; m < 16; m += 4) {
            int e[4], en[4], s[4];
            float a[4][8];
            uint4 v[4];
            #pragma unroll
            for (int i = 0; i < 4; i++) {
                int row = row0 + m + i;
                e[i] = rowPtr[row] + gph;
                en[i] = rowPtr[row + 1];
                #pragma unroll
                for (int j = 0; j < 8; j++) a[i][j] = 0.0f;
            }
            if (gph == 0) {
                #pragma unroll
                for (int i = 0; i < 4; i++) {
                    uint4 sv = y4[(size_t)(row0 + m + i) * 8 + cc];
                    float f[8]; unpack8(sv, f);
                    #pragma unroll
                    for (int j = 0; j < 8; j++) a[i][j] = eps1 * f[j];
                }
            }
            #pragma unroll
            for (int i = 0; i < 4; i++) s[i] = (e[i] < en[i]) ? csr_src[e[i]] : -1;
            #pragma unroll
            for (int i = 0; i < 4; i++) if (s[i] >= 0) v[i] = y4[(size_t)s[i] * 8 + cc];

            int mx = max(max(s[0], s[1]), max(s[2], s[3]));
            while (mx >= 0) {
                int n[4]; uint4 p[4];
                #pragma unroll
                for (int i = 0; i < 4; i++) {
                    n[i] = -1;
                    if (s[i] >= 0) { e[i] += 8; n[i] = (e[i] < en[i]) ? csr_src[e[i]] : -1; }
                }
                #pragma unroll
                for (int i = 0; i < 4; i++) if (n[i] >= 0) p[i] = y4[(size_t)n[i] * 8 + cc];
                #pragma unroll
                for (int i = 0; i < 4; i++) {
                    if (s[i] >= 0) {
                        float f[8]; unpack8(v[i], f);
                        #pragma unroll
                        for (int j = 0; j < 8; j++) a[i][j] += f[j];
                    }
                    s[i] = n[i]; v[i] = p[i];
                }
                mx = max(max(s[0], s[1]), max(s[2], s[3]));
            }

            #pragma unroll
            for (int off = 8; off < 64; off <<= 1)
                #pragma unroll
                for (int i = 0; i < 4; i++)
                    #pragma unroll
                    for (int j = 0; j < 8; j++)
                        a[i][j] += __shfl_xor(a[i][j], off, 64);

            if (gph == 0) {
                #pragma unroll
                for (int i = 0; i < 4; i++) {
                    half8 hv;
                    #pragma unroll
                    for (int j = 0; j < 8; j++)
                        hv[j] = (_Float16)fmaxf(a[i][j] + bav[j], 0.0f);
                    int slot = (cc >> 2) * 64 + (cc & 3) * 16 + (m + i);
                    *(half8*)(s_Aw + (size_t)aswz(slot) * 8) = hv;
                }
            }
        }

        half8 af2[2];
        #pragma unroll
        for (int kc = 0; kc < 2; kc++)
            af2[kc] = *(const half8*)(s_Aw + (size_t)aswz(kc * 64 + lane) * 8);
        floatx4 acc2[4] = {};
        #pragma unroll
        for (int nt = 0; nt < 4; nt++)
            #pragma unroll
            for (int kc = 0; kc < 2; kc++) {
                half8 bf = *(const half8*)(s_B2 + ((size_t)(kc * 4 + nt) * 64 + lane) * 8);
                acc2[nt] = __builtin_amdgcn_mfma_f32_16x16x32_f16(af2[kc], bf, acc2[nt], 0, 0, 0);
            }

        #pragma unroll
        for (int nt = 0; nt < 4; nt++)
            #pragma unroll
            for (int r = 0; r < 4; r++) {
                float val = fmaxf(acc2[nt][r] + bbv[nt], 0.0f);
                bn_s[nt] += val;
                bn_q[nt] += val * val;
                s_Aw[(q * 4 + r) * 64 + nt * 16 + mm] = (_Float16)val;
            }
        half8 t0 = *(const half8*)(s_Aw + lane * 8);
        half8 t1 = *(const half8*)(s_Aw + 512 + lane * 8);
        half8* dst = (half8*)((_Float16*)h_out + (size_t)row0 * 64);
        dst[lane] = t0;
        dst[64 + lane] = t1;
    }

    #pragma unroll
    for (int nt = 0; nt < 4; nt++) {
        bn_s[nt] += __shfl_xor(bn_s[nt], 16, 64);
        bn_s[nt] += __shfl_xor(bn_s[nt], 32, 64);
        bn_q[nt] += __shfl_xor(bn_q[nt], 16, 64);
        bn_q[nt] += __shfl_xor(bn_q[nt], 32, 64);
    }
    __syncthreads();
    if (lane < 16) {
        #pragma unroll
        for (int nt = 0; nt < 4; nt++) s_red[w][nt * 16 + lane] = bn_s[nt];
    }
    __syncthreads();
    if (w == 0) {
        float s = 0;
        #pragma unroll
        for (int j = 0; j < 8; j++) s += s_red[j][lane];
        atomicAdd(&stats_out[lane], s);
    }
    __syncthreads();
    if (lane < 16) {
        #pragma unroll
        for (int nt = 0; nt < 4; nt++) s_red[w][nt * 16 + lane] = bn_q[nt];
    }
    __syncthreads();
    if (w == 0) {
        float s = 0;
        #pragma unroll
        for (int j = 0; j < 8; j++) s += s_red[j][lane];
        atomicAdd(&stats_out[64 + lane], s);
    }
}

// ---------------- final: BN+ReLU of layer 3 (fp16 h), then (N,64)@(64,10)+b ----------------
__global__ __launch_bounds__(256) void final_linear_kernel(
    const ushort* __restrict__ h, const float* __restrict__ stats,
    const float* __restrict__ g, const float* __restrict__ be,
    const float* __restrict__ w, const float* __restrict__ b,
    float* __restrict__ out)
{
    __shared__ float s_w[640];
    __shared__ float s_b[10];
    __shared__ float s_scale[64];
    __shared__ float s_shift[64];
    for (int i = threadIdx.x; i < 640; i += 256) s_w[i] = w[i];
    if (threadIdx.x < 10) s_b[threadIdx.x] = b[threadIdx.x];
    if (threadIdx.x < 64) {
        int c = threadIdx.x;
        float mean = stats[c] * (1.0f / NN);
        float var  = stats[64 + c] * (1.0f / NN) - mean * mean;
        float rstd = rsqrtf(var + BN_EPS);
        float s    = rstd * g[c];
        s_scale[c] = s;
        s_shift[c] = be[c] - mean * s;
    }
    __syncthreads();
    int row = blockIdx.x * 256 + threadIdx.x;
    if (row >= NN) return;
    float acc[10];
    #pragma unroll
    for (int c = 0; c < 10; c++) acc[c] = s_b[c];
    const uint4* hr = (const uint4*)(h + (size_t)row * 64);
    #pragma unroll
    for (int ch = 0; ch < 8; ch++) {
        uint4 v = hr[ch];
        float f[8]; unpack8(v, f);
        #pragma unroll
        for (int j = 0; j < 8; j++) {
            int k = ch * 8 + j;
            float val = fmaxf(fmaf(f[j], s_scale[k], s_shift[k]), 0.0f);
            #pragma unroll
            for (int c = 0; c < 10; c++) acc[c] = fmaf(val, s_w[k * 10 + c], acc[c]);
        }
    }
    #pragma unroll
    for (int c = 0; c < 10; c++) out[row * 10 + c] = acc[c];
}

extern "C" void kernel_launch(void* const* d_in, const int* in_sizes, int n_in,
                              void* d_out, int out_size, void* d_ws, size_t ws_size,
                              hipStream_t stream)
{
    const float* x  = (const float*)d_in[0];
    const int*   ei = (const int*)d_in[1];
    const int E = in_sizes[1] / 2;

    const float* eps[3]; const float* wa[3]; const float* ba[3];
    const float* wb[3];  const float* bb[3]; const float* g[3]; const float* be[3];
    for (int i = 0; i < 3; i++) {
        int base = 2 + 7 * i;
        eps[i] = (const float*)d_in[base + 0];
        wa[i]  = (const float*)d_in[base + 1];
        ba[i]  = (const float*)d_in[base + 2];
        wb[i]  = (const float*)d_in[base + 3];
        bb[i]  = (const float*)d_in[base + 4];
        g[i]   = (const float*)d_in[base + 5];
        be[i]  = (const float*)d_in[base + 6];
    }
    const float* lin_w = (const float*)d_in[23];
    const float* lin_b = (const float*)d_in[24];
    float* out = (float*)d_out;

    // workspace layout: gcur and stats adjacent -> single zeroing memset
    char*  base   = (char*)d_ws;
    int*   gcur   = (int*)base;               // 512 ints
    float* stats  = (float*)(gcur + 512);     // 384 floats (3*128)
    int*   rowPtr = (int*)(stats + 384);      // NN+1
    uint*  bucket = (uint*)(rowPtr + NN + 1); // NCHUNK*CHCAP
    int*   csrsrc = (int*)(bucket + (size_t)NCHUNK * CHCAP);  // E
    size_t ioff   = (char*)(csrsrc + E) - base;
    ushort* yb    = (ushort*)(base + ((ioff + 15) & ~(size_t)15));  // NN*64
    ushort* hA    = yb + (size_t)NN * 64;     // NN*64
    ushort* hB    = hA + (size_t)NN * 64;     // NN*64

    // ---- CSR build (bucketed) ----
    hipMemsetAsync(gcur, 0, (512 + 384) * sizeof(int), stream);
    sortA_kernel<<<(E + SLAB - 1) / SLAB, 256, 0, stream>>>(ei, gcur, bucket, E);
    fillB_kernel<<<NCHUNK, 256, 0, stream>>>(bucket, gcur, rowPtr, csrsrc);

    const int PB = (NGROUP + 3) / 4;   // 782 proj blocks
    const int GB = (NGROUP + 7) / 8;   // 391 gather blocks (1 wave per group)

    // ---- layer 1: proj x (fp32,128) -> y; fused gather+MLP ----
    proj_kernel<128, false><<<PB, 256, 0, stream>>>(
        x, nullptr, nullptr, nullptr, wa[0], yb);
    gin_gather_kernel<<<GB, 512, 0, stream>>>(
        yb, rowPtr, csrsrc, eps[0], ba[0], wb[0], bb[0], hA, stats);
    // ---- layer 2 ----
    proj_kernel<64, true><<<PB, 256, 0, stream>>>(
        hA, stats, g[0], be[0], wa[1], yb);
    gin_gather_kernel<<<GB, 512, 0, stream>>>(
        yb, rowPtr, csrsrc, eps[1], ba[1], wb[1], bb[1], hB, stats + 128);
    // ---- layer 3 ----
    proj_kernel<64, true><<<PB, 256, 0, stream>>>(
        hB, stats + 128, g[1], be[1], wa[2], yb);
    gin_gather_kernel<<<GB, 512, 0, stream>>>(
        yb, rowPtr, csrsrc, eps[2], ba[2], wb[2], bb[2], hA, stats + 256);
    // ---- final ----
    final_linear_kernel<<<(NN + 255) / 256, 256, 0, stream>>>(
        hA, stats + 256, g[2], be[2], lin_w, lin_b, out);
}